// Round 17
// baseline (123.718 us; speedup 1.0000x reference)
//
#include <hip/hip_runtime.h>
#include <hip/hip_bf16.h>
#include <math.h>

// MAB: q=QWq^T+bq; k=KWk^T+bk; v=KWv^T+bv; per-head softmax(qk^T/16)v + q-residual;
// LN0; +relu(GEMM Wo); LN1.  B=4, N=2048, D=256, H=4, Dh=64.
// Round 17: attn v11 on mfma_f32_32x32x16_bf16 -- half the MFMA instructions
// and half the LDS reads per q-row vs the 16x16x32 structure. 256-thr blocks
// (2 KV-groups x 2 q-waves of 32 q), dbuf 64KB, v6 loop skeleton, no-max
// softmax, in-register P via single permlane32_swap per word-pair.
// proj2 + fused_out byte-identical to round 15/16 (validated).
// ws (8 MB): [0,4MB) k bf16 [8192][256]; [4,8MB) v_t bf16 [16][64][2048].

typedef __attribute__((ext_vector_type(8))) short bf16x8;
typedef __attribute__((ext_vector_type(4))) float f32x4;
typedef __attribute__((ext_vector_type(16))) float f32x16;

static __device__ __forceinline__ unsigned short f2bf(float x) {
  return __bfloat16_as_ushort(__float2bfloat16(x));
}
static __device__ __forceinline__ int pk2(float lo, float hi) {
  return (int)((unsigned)f2bf(lo) | ((unsigned)f2bf(hi) << 16));
}
static __device__ __forceinline__ float exp2_fast(float x) {
  float r; asm("v_exp_f32 %0, %1" : "=v"(r) : "v"(x)); return r;
}

#define SWZ(row, col) ((col) ^ (((row) & 7) << 3))

typedef unsigned short tile64_t[64][64];

// ---------------------------------------------------------------------------
// proj2 (validated): A-slab-reuse projections. grid (2, 128, 3), 256 threads.
// ---------------------------------------------------------------------------
__global__ __launch_bounds__(256, 2) void proj2_kernel(
    const float* __restrict__ Q, const float* __restrict__ K,
    const float* __restrict__ Wq, const float* __restrict__ bq,
    const float* __restrict__ Wk, const float* __restrict__ bk,
    const float* __restrict__ Wv, const float* __restrict__ bv,
    float* __restrict__ qout, unsigned short* __restrict__ kbf,
    unsigned short* __restrict__ vtb)
{
  __shared__ __align__(16) unsigned short Ab[64][256];
  __shared__ __align__(16) unsigned short Wb[64][64];
  const int tid = threadIdx.x;
  const int z = blockIdx.z;
  const int bm = blockIdx.y;

  const float* A    = (z == 0) ? Q  : K;
  const float* W    = (z == 0) ? Wq : ((z == 1) ? Wk : Wv);
  const float* bias = (z == 0) ? bq : ((z == 1) ? bk : bv);

  const int wid = tid >> 6, lane = tid & 63;
  const int l15 = lane & 15, g = lane >> 4;
  const int wr = wid >> 1, wc = wid & 1;
  const float* Ablk = A + (size_t)bm * 64 * 256;

  const int sr = tid >> 2, sc = (tid & 3) * 16;
  const int c0 = SWZ(sr, sc), c1 = SWZ(sr, sc + 8);

  #pragma unroll
  for (int kb = 0; kb < 4; ++kb) {
    const float* ap = Ablk + (size_t)sr*256 + kb*64 + sc;
    float4 a0 = *(const float4*)ap,       a1 = *(const float4*)(ap + 4);
    float4 a2 = *(const float4*)(ap + 8), a3 = *(const float4*)(ap + 12);
    int4 p0 = { pk2(a0.x,a0.y), pk2(a0.z,a0.w), pk2(a1.x,a1.y), pk2(a1.z,a1.w) };
    int4 p1 = { pk2(a2.x,a2.y), pk2(a2.z,a2.w), pk2(a3.x,a3.y), pk2(a3.z,a3.w) };
    *(int4*)&Ab[sr][kb*64 + c0] = p0;
    *(int4*)&Ab[sr][kb*64 + c1] = p1;
  }

  for (int bi = 0; bi < 2; ++bi) {
    const int bn = blockIdx.x + bi*2;
    const float* Wblk = W + (size_t)bn * 64 * 256;

    f32x4 acc[2][2];
    #pragma unroll
    for (int i = 0; i < 2; ++i)
      #pragma unroll
      for (int j = 0; j < 2; ++j)
        #pragma unroll
        for (int r = 0; r < 4; ++r) acc[i][j][r] = 0.f;

    for (int k0 = 0; k0 < 256; k0 += 64) {
      if (bi | k0) __syncthreads();
      {
        const float* wp = Wblk + (size_t)sr*256 + k0 + sc;
        float4 w0 = *(const float4*)wp,       w1 = *(const float4*)(wp + 4);
        float4 w2 = *(const float4*)(wp + 8), w3 = *(const float4*)(wp + 12);
        int4 p0 = { pk2(w0.x,w0.y), pk2(w0.z,w0.w), pk2(w1.x,w1.y), pk2(w1.z,w1.w) };
        int4 p1 = { pk2(w2.x,w2.y), pk2(w2.z,w2.w), pk2(w3.x,w3.y), pk2(w3.z,w3.w) };
        *(int4*)&Wb[sr][c0] = p0;
        *(int4*)&Wb[sr][c1] = p1;
      }
      __syncthreads();

      __builtin_amdgcn_s_setprio(1);
      #pragma unroll
      for (int kc = 0; kc < 64; kc += 32) {
        bf16x8 af[2], bf_[2];
        #pragma unroll
        for (int i = 0; i < 2; ++i) {
          int ra = wr*32 + i*16 + l15;
          int rb = wc*32 + i*16 + l15;
          if (z == 2) {
            af[i]  = *(const bf16x8*)&Wb[ra][SWZ(ra, kc + g*8)];
            bf_[i] = *(const bf16x8*)&Ab[rb][k0 + SWZ(rb, kc + g*8)];
          } else {
            af[i]  = *(const bf16x8*)&Ab[ra][k0 + SWZ(ra, kc + g*8)];
            bf_[i] = *(const bf16x8*)&Wb[rb][SWZ(rb, kc + g*8)];
          }
        }
        #pragma unroll
        for (int i = 0; i < 2; ++i)
          #pragma unroll
          for (int j = 0; j < 2; ++j)
            acc[i][j] = __builtin_amdgcn_mfma_f32_16x16x32_bf16(af[i], bf_[j], acc[i][j], 0, 0, 0);
      }
      __builtin_amdgcn_s_setprio(0);
    }

    if (z == 2) {
      const int bvb = bm >> 5;
      const int n0 = (bm & 31) * 64 + wc*32;
      #pragma unroll
      for (int di = 0; di < 2; ++di)
        #pragma unroll
        for (int r = 0; r < 4; ++r) {
          int d = wr*32 + di*16 + g*4 + r;
          float bvs = bias[bn*64 + d];
          #pragma unroll
          for (int ni = 0; ni < 2; ++ni) {
            float c = acc[di][ni][r] + bvs;
            vtb[((size_t)(bvb*4 + bn)*64 + d)*2048 + n0 + ni*16 + l15] = f2bf(c);
          }
        }
    } else {
      const int gm = bm*64 + wr*32, ge = bn*64 + wc*32;
      float bv0 = bias[ge + l15], bv1 = bias[ge + 16 + l15];
      #pragma unroll
      for (int mi = 0; mi < 2; ++mi)
        #pragma unroll
        for (int r = 0; r < 4; ++r) {
          int row = gm + mi*16 + g*4 + r;
          #pragma unroll
          for (int ei = 0; ei < 2; ++ei) {
            float c = acc[mi][ei][r] + (ei ? bv1 : bv0);
            if (z == 0) qout[(size_t)row*256 + ge + ei*16 + l15] = c;
            else        kbf [(size_t)row*256 + ge + ei*16 + l15] = f2bf(c);
          }
        }
    }
  }
}

// ---------------------------------------------------------------------------
// attn v11: 32x32x16 MFMA. 256 thr = 4 waves: grp = wid>>1 (KV half, 16 tiles
// of 64 k'), qw = wid&1 (32 q-rows). Per-lane q = lane&31, hi = lane>>5.
// S^T C-layout: k' = (reg&3)+8*(reg>>2)+4*hi (+st*32), q = lane&31.
// PV B-frag via pk pairs + permlane32_swap: swap(pk[4c'],pk[4c'+2]) -> j01,j45.
// Dbuf 64KB LDS, v6 loop skeleton (1 barrier/tile), no-max exp2 softmax.
// 512 blocks XCD-swizzled. 2-way plain-sum merge.
// ---------------------------------------------------------------------------
__global__ __launch_bounds__(256, 2) void attn_mfma11(
    const float* __restrict__ q,
    const unsigned short* __restrict__ kb,
    const unsigned short* __restrict__ vt,
    float* __restrict__ o)
{
  extern __shared__ __align__(16) char smem_dyn[];
  tile64_t* Ks = (tile64_t*)smem_dyn;             // [grp*2+buf], 32 KB
  tile64_t* Vt = (tile64_t*)(smem_dyn + 32768);   // [grp*2+buf], 32 KB

  const int tid = threadIdx.x;
  const int wid = tid >> 6;        // 0..3
  const int grp = wid >> 1;        // KV half
  const int qw  = wid & 1;         // q half (32 rows)
  const int lane = tid & 63;
  const int l31 = lane & 31;
  const int hi  = lane >> 5;
  const int lin = blockIdx.x;
  const int xcd = lin & 7, idx = lin >> 3;
  const int bh = xcd * 2 + (idx >> 5);
  const int qb = idx & 31;
  const int b = bh >> 2, h = bh & 3;

  const float qscale = 0.0625f * 1.44269504089f;   // 1/sqrt(256) * log2(e)
  // Q B-fragments: lane holds q-row (qw*32+l31), d = step*16 + hi*8 + j
  bf16x8 qf[4];
  {
    const float* qp = q + ((size_t)(b*2048 + qb*64 + qw*32 + l31))*256 + h*64;
    #pragma unroll
    for (int step = 0; step < 4; ++step) {
      union { bf16x8 v; unsigned short s[8]; } tmp;
      #pragma unroll
      for (int j = 0; j < 8; ++j)
        tmp.s[j] = f2bf(qp[step*16 + hi*8 + j] * qscale);
      qf[step] = tmp.v;
    }
  }

  // staging: grp's 2 waves (128 thr) stage K (8KB) + V (8KB) per tile.
  const int gt = tid & 127;
  const int sr = gt >> 1;                  // 0..63 (K row = k'; V row = d)
  const int scb = (gt & 1) * 32;           // short-col base (0 or 32)
  int cols[4];
  #pragma unroll
  for (int i = 0; i < 4; ++i) cols[i] = SWZ(sr, scb + 8*i);
  const unsigned short* kgp = kb + ((size_t)(b*2048 + grp*1024 + sr))*256 + h*64 + scb;
  const unsigned short* vgp = vt + ((size_t)(bh*64 + sr))*2048 + grp*1024 + scb;

  f32x16 sa0, sa1, oa0, oa1;
  #pragma unroll
  for (int r = 0; r < 16; ++r) { oa0[r] = 0.f; oa1[r] = 0.f; }
  float l_ = 0.f;

  // prologue: tile 0 -> buf0 direct; prefetch tile-1 regs
  #pragma unroll
  for (int i = 0; i < 4; ++i) {
    *(int4*)&Ks[grp*2+0][sr][cols[i]] = *(const int4*)(kgp + 8*i);
    *(int4*)&Vt[grp*2+0][sr][cols[i]] = *(const int4*)(vgp + 8*i);
  }
  int4 kR[4], vR[4];
  #pragma unroll
  for (int i = 0; i < 4; ++i) {
    kR[i] = *(const int4*)(kgp + (size_t)64*256 + 8*i);
    vR[i] = *(const int4*)(vgp + 64 + 8*i);
  }
  __syncthreads();

  for (int kt = 0; kt < 16; ++kt) {
    const int cur = kt & 1;
    const tile64_t& Kc = Ks[grp*2 + cur];
    const tile64_t& Vc = Vt[grp*2 + cur];

    // ---- S^T: two 32x32 tiles (st = k'-subtile), K=64 over 4 steps
    #pragma unroll
    for (int r = 0; r < 16; ++r) { sa0[r] = 0.f; sa1[r] = 0.f; }
    __builtin_amdgcn_s_setprio(1);
    #pragma unroll
    for (int step = 0; step < 4; ++step) {
      bf16x8 af0 = *(const bf16x8*)&Kc[l31     ][SWZ(l31, step*16 + hi*8)];
      bf16x8 af1 = *(const bf16x8*)&Kc[32 + l31][SWZ(l31, step*16 + hi*8)];
      sa0 = __builtin_amdgcn_mfma_f32_32x32x16_bf16(af0, qf[step], sa0, 0, 0, 0);
      sa1 = __builtin_amdgcn_mfma_f32_32x32x16_bf16(af1, qf[step], sa1, 0, 0, 0);
    }
    __builtin_amdgcn_s_setprio(0);

    // ---- no-max softmax; pack bf16 pairs: pk[st][r2] = (p[2r2], p[2r2+1])
    float ps = 0.f;
    unsigned pk0[8], pk1[8];
    #pragma unroll
    for (int r2 = 0; r2 < 8; ++r2) {
      float p0 = exp2_fast(sa0[2*r2]);
      float p1 = exp2_fast(sa0[2*r2 + 1]);
      ps += p0 + p1;
      pk0[r2] = (unsigned)pk2(p0, p1);
    }
    #pragma unroll
    for (int r2 = 0; r2 < 8; ++r2) {
      float p0 = exp2_fast(sa1[2*r2]);
      float p1 = exp2_fast(sa1[2*r2 + 1]);
      ps += p0 + p1;
      pk1[r2] = (unsigned)pk2(p0, p1);
    }
    ps += __shfl_xor(ps, 32, 64);   // lane & lane+32 share q = lane&31
    l_ += ps;

    // ---- O^T += V^T P^T: k' chunks c = 0..3 (16 each); B-frag via swaps
    __builtin_amdgcn_s_setprio(1);
    #pragma unroll
    for (int c = 0; c < 4; ++c) {
      const int c1 = c & 1;
      unsigned X, Z, Y, W;
      if (c < 2) { X = pk0[4*c1+0]; Z = pk0[4*c1+1]; Y = pk0[4*c1+2]; W = pk0[4*c1+3]; }
      else       { X = pk1[4*c1+0]; Z = pk1[4*c1+1]; Y = pk1[4*c1+2]; W = pk1[4*c1+3]; }
      // swap32(X,Y): X -> j01 word (lo keeps, hi gets lo-lane's Y);
      //              Y -> j45 word (lo gets hi-lane's X, hi keeps).
      asm volatile("v_permlane32_swap_b32 %0, %1" : "+v"(X), "+v"(Y));
      asm volatile("v_permlane32_swap_b32 %0, %1" : "+v"(Z), "+v"(W));
      int4 pw = { (int)X, (int)Z, (int)Y, (int)W };   // j01, j23, j45, j67
      bf16x8 pf = __builtin_bit_cast(bf16x8, pw);
      bf16x8 vf0 = *(const bf16x8*)&Vc[l31     ][SWZ(l31, c*16 + hi*8)];
      bf16x8 vf1 = *(const bf16x8*)&Vc[32 + l31][SWZ(l31, c*16 + hi*8)];
      oa0 = __builtin_amdgcn_mfma_f32_32x32x16_bf16(vf0, pf, oa0, 0, 0, 0);
      oa1 = __builtin_amdgcn_mfma_f32_32x32x16_bf16(vf1, pf, oa1, 0, 0, 0);
    }
    __builtin_amdgcn_s_setprio(0);

    // ---- stage tile kt+1 into other buffer; prefetch kt+2 regs
    if (kt < 15) {
      #pragma unroll
      for (int i = 0; i < 4; ++i) {
        *(int4*)&Ks[grp*2+(cur^1)][sr][cols[i]] = kR[i];
        *(int4*)&Vt[grp*2+(cur^1)][sr][cols[i]] = vR[i];
      }
      if (kt < 14) {
        const unsigned short* kn = kgp + (size_t)(kt + 2) * 64 * 256;
        const unsigned short* vn = vgp + (kt + 2) * 64;
        #pragma unroll
        for (int i = 0; i < 4; ++i) {
          kR[i] = *(const int4*)(kn + 8*i);
          vR[i] = *(const int4*)(vn + 8*i);
        }
      }
    }
    __syncthreads();
  }

  // ---- 2-way merge (plain sums); LDS tiles dead
  float* cob = (float*)smem_dyn;            // [64 d][64 q] f32, 16 KB
  float* cml = (float*)(smem_dyn + 16384);  // [64] f32
  const int qloc = qw*32 + l31;
  if (grp == 1) {
    #pragma unroll
    for (int reg = 0; reg < 16; ++reg) {
      int dr = (reg & 3) + 8*(reg >> 2) + 4*hi;
      cob[(dr     )*64 + qloc] = oa0[reg];
      cob[(dr + 32)*64 + qloc] = oa1[reg];
    }
    cml[qloc] = l_;   // lanes l, l+32 write same value (post-shfl) - benign
  }
  __syncthreads();
  if (grp == 0) {
    float linv = 1.0f / (l_ + cml[qloc]);
    float* op = o + ((size_t)(b*2048 + qb*64 + qloc))*256 + h*64;
    #pragma unroll
    for (int dt = 0; dt < 2; ++dt) {
      #pragma unroll
      for (int rr = 0; rr < 4; ++rr) {
        const int dbase = dt*32 + 8*rr + 4*hi;
        float4 qv = *(const float4*)(op + dbase);
        float4 st;
        #pragma unroll
        for (int j = 0; j < 4; ++j) {
          float own = dt ? oa1[4*rr + j] : oa0[4*rr + j];
          float oth = cob[(dbase + j)*64 + qloc];
          ((float*)&st)[j] = ((const float*)&qv)[j] + (own + oth) * linv;
        }
        *(float4*)(op + dbase) = st;
      }
    }
  }
}

// ---------------------------------------------------------------------------
// fused_out (validated, byte-identical): LN0 + res+relu(GEMM Wo) + LN1.
// ---------------------------------------------------------------------------
__global__ __launch_bounds__(512) void fused_out(
    const float* __restrict__ x, const float* __restrict__ Wo,
    const float* __restrict__ bo,
    const float* __restrict__ g0v, const float* __restrict__ b0v,
    const float* __restrict__ g1v, const float* __restrict__ b1v,
    float* __restrict__ y)
{
  __shared__ __align__(16) unsigned short As[32][256];
  __shared__ __align__(16) unsigned short Ws[256][64];
  __shared__ float mu_[32], rs_[32];
  float* P = (float*)&Ws[0][0];

  const int tid = threadIdx.x;
  const int w = tid >> 6, lane = tid & 63;
  const int l15 = lane & 15, g = lane >> 4;
  const int r0 = blockIdx.x * 32;

  {
    float4 g4 = *(const float4*)(g0v + lane*4);
    float4 b4 = *(const float4*)(b0v + lane*4);
    #pragma unroll
    for (int rr = 0; rr < 4; ++rr) {
      int m = w*4 + rr;
      const float* xr = x + (size_t)(r0 + m) * 256;
      float4 v = *(const float4*)(xr + lane*4);
      float s = v.x + v.y + v.z + v.w;
      #pragma unroll
      for (int mk = 1; mk <= 32; mk <<= 1) s += __shfl_xor(s, mk, 64);
      float mu = s * (1.0f/256.0f);
      float dx = v.x-mu, dy = v.y-mu, dz = v.z-mu, dw = v.w-mu;
      float qq = dx*dx + dy*dy + dz*dz + dw*dw;
      #pragma unroll
      for (int mk = 1; mk <= 32; mk <<= 1) qq += __shfl_xor(qq, mk, 64);
      float rstd = rsqrtf(qq * (1.0f/256.0f) + 1e-5f);
      if (lane == 0) { mu_[m] = mu; rs_[m] = rstd; }
      float nx = dx*rstd*g4.x + b4.x;
      float ny = dy*rstd*g4.y + b4.y;
      float nz = dz*rstd*g4.z + b4.z;
      float nw = dw*rstd*g4.w + b4.w;
      int2 pv = { pk2(nx, ny), pk2(nz, nw) };
      *(int2*)&As[m][SWZ(m, lane*4)] = pv;
    }
  }
  __syncthreads();

  const int m0 = (w >> 2) * 16;
  const int e0 = (w & 3) * 64;
  f32x4 acc4[4];
  #pragma unroll
  for (int j = 0; j < 4; ++j)
    #pragma unroll
    for (int r = 0; r < 4; ++r) acc4[j][r] = 0.f;

  for (int k0 = 0; k0 < 256; k0 += 64) {
    if (k0) __syncthreads();
    {
      const int ch = tid & 7;
      const int er = tid >> 3;
      #pragma unroll
      for (int p = 0; p < 4; ++p) {
        int e = p*64 + er;
        const float* wp = Wo + (size_t)e*256 + k0 + ch*8;
        float4 u0 = *(const float4*)wp;
        float4 u1 = *(const float4*)(wp + 4);
        int4 pk = { pk2(u0.x,u0.y), pk2(u0.z,u0.w), pk2(u1.x,u1.y), pk2(u1.z,u1.w) };
        *(int4*)&Ws[e][SWZ(e, ch*8)] = pk;
      }
    }
    __syncthreads();
    __builtin_amdgcn_s_setprio(1);
    #pragma unroll
    for (int ds_ = 0; ds_ < 2; ++ds_) {
      int ma = m0 + l15;
      bf16x8 af = *(const bf16x8*)&As[ma][SWZ(ma, k0 + ds_*32 + g*8)];
      #pragma unroll
      for (int j = 0; j < 4; ++j) {
        int er = e0 + j*16 + l15;
        bf16x8 bfv = *(const bf16x8*)&Ws[er][SWZ(er, ds_*32 + g*8)];
        acc4[j] = __builtin_amdgcn_mfma_f32_16x16x32_bf16(af, bfv, acc4[j], 0, 0, 0);
      }
    }
    __builtin_amdgcn_s_setprio(0);
  }
  __syncthreads();

  #pragma unroll
  for (int j = 0; j < 4; ++j) {
    int e = e0 + j*16 + l15;
    float bov = bo[e], g0e = g0v[e], b0e = b0v[e];
    #pragma unroll
    for (int r = 0; r < 4; ++r) {
      int m = m0 + g*4 + r;
      float xv = x[(size_t)(r0 + m)*256 + e];
      float resv = (xv - mu_[m]) * rs_[m] * g0e + b0e;
      float val = acc4[j][r] + bov;
      P[m*256 + e] = resv + fmaxf(val, 0.f);
    }
  }
  __syncthreads();

  {
    float4 g4 = *(const float4*)(g1v + lane*4);
    float4 b4 = *(const float4*)(b1v + lane*4);
    #pragma unroll
    for (int rr = 0; rr < 4; ++rr) {
      int m = w*4 + rr;
      float4 v = *(const float4*)&P[m*256 + lane*4];
      float s = v.x + v.y + v.z + v.w;
      #pragma unroll
      for (int mk = 1; mk <= 32; mk <<= 1) s += __shfl_xor(s, mk, 64);
      float mu = s * (1.0f/256.0f);
      float dx = v.x-mu, dy = v.y-mu, dz = v.z-mu, dw = v.w-mu;
      float qq = dx*dx + dy*dy + dz*dz + dw*dw;
      #pragma unroll
      for (int mk = 1; mk <= 32; mk <<= 1) qq += __shfl_xor(qq, mk, 64);
      float rstd = rsqrtf(qq * (1.0f/256.0f) + 1e-5f);
      float4 o;
      o.x = dx*rstd*g4.x + b4.x; o.y = dy*rstd*g4.y + b4.y;
      o.z = dz*rstd*g4.z + b4.z; o.w = dw*rstd*g4.w + b4.w;
      *(float4*)(y + (size_t)(r0 + m)*256 + lane*4) = o;
    }
  }
}

// ---------------------------------------------------------------------------
extern "C" void kernel_launch(void* const* d_in, const int* in_sizes, int n_in,
                              void* d_out, int out_size, void* d_ws, size_t ws_size,
                              hipStream_t stream) {
  const float* Q  = (const float*)d_in[0];
  const float* K  = (const float*)d_in[1];
  const float* Wq = (const float*)d_in[2];
  const float* bq = (const float*)d_in[3];
  const float* Wk = (const float*)d_in[4];
  const float* bk = (const float*)d_in[5];
  const float* Wv = (const float*)d_in[6];
  const float* bv = (const float*)d_in[7];
  const float* Wo = (const float*)d_in[8];
  const float* bo = (const float*)d_in[9];
  const float* g0 = (const float*)d_in[10];
  const float* b0 = (const float*)d_in[11];
  const float* g1 = (const float*)d_in[12];
  const float* b1 = (const float*)d_in[13];
  float* out = (float*)d_out;

  const size_t SZ = (size_t)4 * 2048 * 256;
  if (ws_size < 2 * SZ * sizeof(unsigned short)) return;  // need 8 MB

  unsigned short* kbf = (unsigned short*)d_ws;
  unsigned short* vtb = kbf + SZ;

  const int ATTN_LDS = 65536;
  hipFuncSetAttribute((const void*)attn_mfma11,
                      hipFuncAttributeMaxDynamicSharedMemorySize, ATTN_LDS);

  proj2_kernel<<<dim3(2, 128, 3), dim3(256), 0, stream>>>(
      Q, K, Wq, bq, Wk, bk, Wv, bv, out, kbf, vtb);
  attn_mfma11<<<dim3(512), dim3(256), ATTN_LDS, stream>>>(out, kbf, vtb, out);
  fused_out<<<dim3(256), dim3(512), 0, stream>>>(out, Wo, bo, g0, b0, g1, b1, out);
}

// Round 18
// 66.424 us; speedup vs baseline: 1.8625x; 1.8625x over previous
//
#include <hip/hip_runtime.h>
#include <hip/hip_bf16.h>
#include <math.h>

// MAB: q=QWq^T+bq; k=KWk^T+bk; v=KWv^T+bv; per-head softmax(qk^T/16)v + q-residual;
// LN0; +relu(GEMM Wo); LN1.  B=4, N=2048, D=256, H=4, Dh=64.
// Round 18: attn v12 = v11's 32x32x16 math (validated) + v8's global_load_lds
// staging (validated) -- removes the kR/vR registers that spilled v11.
// 256 thr = 4 waves (2 KV-grp x 2 qw of 32 q-rows), dbuf 64KB, 1 bar/tile.
// proj2 + fused_out byte-identical to round 15/16 (validated).
// ws (8 MB): [0,4MB) k bf16 [8192][256]; [4,8MB) v_t bf16 [16][64][2048].

typedef __attribute__((ext_vector_type(8))) short bf16x8;
typedef __attribute__((ext_vector_type(4))) float f32x4;
typedef __attribute__((ext_vector_type(16))) float f32x16;

static __device__ __forceinline__ unsigned short f2bf(float x) {
  return __bfloat16_as_ushort(__float2bfloat16(x));
}
static __device__ __forceinline__ int pk2(float lo, float hi) {
  return (int)((unsigned)f2bf(lo) | ((unsigned)f2bf(hi) << 16));
}
static __device__ __forceinline__ float exp2_fast(float x) {
  float r; asm("v_exp_f32 %0, %1" : "=v"(r) : "v"(x)); return r;
}
static __device__ __forceinline__ void gload_lds16(const void* g, void* lds) {
  __builtin_amdgcn_global_load_lds(
      (const __attribute__((address_space(1))) unsigned int*)g,
      (__attribute__((address_space(3))) unsigned int*)lds, 16, 0, 0);
}

#define SWZ(row, col) ((col) ^ (((row) & 7) << 3))

// ---------------------------------------------------------------------------
// proj2 (validated): A-slab-reuse projections. grid (2, 128, 3), 256 threads.
// ---------------------------------------------------------------------------
__global__ __launch_bounds__(256, 2) void proj2_kernel(
    const float* __restrict__ Q, const float* __restrict__ K,
    const float* __restrict__ Wq, const float* __restrict__ bq,
    const float* __restrict__ Wk, const float* __restrict__ bk,
    const float* __restrict__ Wv, const float* __restrict__ bv,
    float* __restrict__ qout, unsigned short* __restrict__ kbf,
    unsigned short* __restrict__ vtb)
{
  __shared__ __align__(16) unsigned short Ab[64][256];
  __shared__ __align__(16) unsigned short Wb[64][64];
  const int tid = threadIdx.x;
  const int z = blockIdx.z;
  const int bm = blockIdx.y;

  const float* A    = (z == 0) ? Q  : K;
  const float* W    = (z == 0) ? Wq : ((z == 1) ? Wk : Wv);
  const float* bias = (z == 0) ? bq : ((z == 1) ? bk : bv);

  const int wid = tid >> 6, lane = tid & 63;
  const int l15 = lane & 15, g = lane >> 4;
  const int wr = wid >> 1, wc = wid & 1;
  const float* Ablk = A + (size_t)bm * 64 * 256;

  const int sr = tid >> 2, sc = (tid & 3) * 16;
  const int c0 = SWZ(sr, sc), c1 = SWZ(sr, sc + 8);

  #pragma unroll
  for (int kb = 0; kb < 4; ++kb) {
    const float* ap = Ablk + (size_t)sr*256 + kb*64 + sc;
    float4 a0 = *(const float4*)ap,       a1 = *(const float4*)(ap + 4);
    float4 a2 = *(const float4*)(ap + 8), a3 = *(const float4*)(ap + 12);
    int4 p0 = { pk2(a0.x,a0.y), pk2(a0.z,a0.w), pk2(a1.x,a1.y), pk2(a1.z,a1.w) };
    int4 p1 = { pk2(a2.x,a2.y), pk2(a2.z,a2.w), pk2(a3.x,a3.y), pk2(a3.z,a3.w) };
    *(int4*)&Ab[sr][kb*64 + c0] = p0;
    *(int4*)&Ab[sr][kb*64 + c1] = p1;
  }

  for (int bi = 0; bi < 2; ++bi) {
    const int bn = blockIdx.x + bi*2;
    const float* Wblk = W + (size_t)bn * 64 * 256;

    f32x4 acc[2][2];
    #pragma unroll
    for (int i = 0; i < 2; ++i)
      #pragma unroll
      for (int j = 0; j < 2; ++j)
        #pragma unroll
        for (int r = 0; r < 4; ++r) acc[i][j][r] = 0.f;

    for (int k0 = 0; k0 < 256; k0 += 64) {
      if (bi | k0) __syncthreads();
      {
        const float* wp = Wblk + (size_t)sr*256 + k0 + sc;
        float4 w0 = *(const float4*)wp,       w1 = *(const float4*)(wp + 4);
        float4 w2 = *(const float4*)(wp + 8), w3 = *(const float4*)(wp + 12);
        int4 p0 = { pk2(w0.x,w0.y), pk2(w0.z,w0.w), pk2(w1.x,w1.y), pk2(w1.z,w1.w) };
        int4 p1 = { pk2(w2.x,w2.y), pk2(w2.z,w2.w), pk2(w3.x,w3.y), pk2(w3.z,w3.w) };
        *(int4*)&Wb[sr][c0] = p0;
        *(int4*)&Wb[sr][c1] = p1;
      }
      __syncthreads();

      __builtin_amdgcn_s_setprio(1);
      #pragma unroll
      for (int kc = 0; kc < 64; kc += 32) {
        bf16x8 af[2], bf_[2];
        #pragma unroll
        for (int i = 0; i < 2; ++i) {
          int ra = wr*32 + i*16 + l15;
          int rb = wc*32 + i*16 + l15;
          if (z == 2) {
            af[i]  = *(const bf16x8*)&Wb[ra][SWZ(ra, kc + g*8)];
            bf_[i] = *(const bf16x8*)&Ab[rb][k0 + SWZ(rb, kc + g*8)];
          } else {
            af[i]  = *(const bf16x8*)&Ab[ra][k0 + SWZ(ra, kc + g*8)];
            bf_[i] = *(const bf16x8*)&Wb[rb][SWZ(rb, kc + g*8)];
          }
        }
        #pragma unroll
        for (int i = 0; i < 2; ++i)
          #pragma unroll
          for (int j = 0; j < 2; ++j)
            acc[i][j] = __builtin_amdgcn_mfma_f32_16x16x32_bf16(af[i], bf_[j], acc[i][j], 0, 0, 0);
      }
      __builtin_amdgcn_s_setprio(0);
    }

    if (z == 2) {
      const int bvb = bm >> 5;
      const int n0 = (bm & 31) * 64 + wc*32;
      #pragma unroll
      for (int di = 0; di < 2; ++di)
        #pragma unroll
        for (int r = 0; r < 4; ++r) {
          int d = wr*32 + di*16 + g*4 + r;
          float bvs = bias[bn*64 + d];
          #pragma unroll
          for (int ni = 0; ni < 2; ++ni) {
            float c = acc[di][ni][r] + bvs;
            vtb[((size_t)(bvb*4 + bn)*64 + d)*2048 + n0 + ni*16 + l15] = f2bf(c);
          }
        }
    } else {
      const int gm = bm*64 + wr*32, ge = bn*64 + wc*32;
      float bv0 = bias[ge + l15], bv1 = bias[ge + 16 + l15];
      #pragma unroll
      for (int mi = 0; mi < 2; ++mi)
        #pragma unroll
        for (int r = 0; r < 4; ++r) {
          int row = gm + mi*16 + g*4 + r;
          #pragma unroll
          for (int ei = 0; ei < 2; ++ei) {
            float c = acc[mi][ei][r] + (ei ? bv1 : bv0);
            if (z == 0) qout[(size_t)row*256 + ge + ei*16 + l15] = c;
            else        kbf [(size_t)row*256 + ge + ei*16 + l15] = f2bf(c);
          }
        }
    }
  }
}

// ---------------------------------------------------------------------------
// attn v12: 32x32x16 MFMA + global_load_lds staging.
// 256 thr = 4 waves: grp = wid>>1 (KV half, 16 tiles of 64 k'), qw = wid&1
// (32 q-rows). Per-lane q = lane&31, hi = lane>>5.
// LDS 64KB dbuf: K[buf][grp] at buf*16384+grp*8192; V at +32768.
// Staging: v8 scheme -- linear LDS dest, source chunk (lane&7)^(lane>>3).
// S^T C-layout (m74/m101): k' = (reg&3)+8*(reg>>2)+4*hi, q = lane&31.
// PV B-frag: pk pairs + permlane32_swap (v11 derivation, validated).
// 512 blocks XCD-swizzled. 2-way plain-sum merge. No-max exp2 softmax.
// ---------------------------------------------------------------------------
__global__ __launch_bounds__(256, 2) void attn_mfma12(
    const float* __restrict__ q,
    const unsigned short* __restrict__ kb,
    const unsigned short* __restrict__ vt,
    float* __restrict__ o)
{
  extern __shared__ __align__(16) char smem_dyn[];

  const int tid = threadIdx.x;
  const int wid = tid >> 6;        // 0..3
  const int grp = wid >> 1;        // KV half
  const int qw  = wid & 1;         // staging row-half & q half
  const int lane = tid & 63;
  const int l31 = lane & 31;
  const int hi  = lane >> 5;
  const int lin = blockIdx.x;
  const int xcd = lin & 7, idx = lin >> 3;
  const int bh = xcd * 2 + (idx >> 5);
  const int qb = idx & 31;
  const int b = bh >> 2, h = bh & 3;

  const float qscale = 0.0625f * 1.44269504089f;   // 1/sqrt(256) * log2(e)
  // Q B-fragments: lane holds q-row (qw*32+l31); d = step*16 + hi*8 + j
  bf16x8 qf[4];
  {
    const float* qp = q + ((size_t)(b*2048 + qb*64 + qw*32 + l31))*256 + h*64;
    #pragma unroll
    for (int step = 0; step < 4; ++step) {
      union { bf16x8 v; unsigned short s[8]; } tmp;
      #pragma unroll
      for (int j = 0; j < 8; ++j)
        tmp.s[j] = f2bf(qp[step*16 + hi*8 + j] * qscale);
      qf[step] = tmp.v;
    }
  }

  // gload_lds staging (v8 scheme): wave (grp,qw) stages rows qw*32..+32 of its
  // grp's K and V tiles. Linear LDS dest; global source chunk pre-swizzled.
  const int lrow = lane >> 3;                         // 0..7
  const int lchk = (lane & 7) ^ lrow;                 // pre-swizzled 16B chunk
  const unsigned short* kL = kb
      + ((size_t)(b*2048 + grp*1024 + qw*32 + lrow))*256 + h*64 + lchk*8;
  const unsigned short* vL = vt
      + ((size_t)(bh*64 + qw*32 + lrow))*2048 + grp*1024 + lchk*8;
  const int ldsKb = grp*8192 + qw*4096;               // + buf*16384 + i*1024
  const int ldsVb = 32768 + grp*8192 + qw*4096;

#define STAGE12(tt, bb) do {                                                  \
    const size_t koff_ = (size_t)(tt)*64*256;                                 \
    const size_t voff_ = (size_t)(tt)*64;                                     \
    _Pragma("unroll")                                                         \
    for (int i_ = 0; i_ < 4; ++i_) {                                          \
      gload_lds16(kL + koff_ + (size_t)i_*8*256,                              \
                  smem_dyn + (bb)*16384 + ldsKb + i_*1024);                   \
      gload_lds16(vL + voff_ + (size_t)i_*8*2048,                             \
                  smem_dyn + (bb)*16384 + ldsVb + i_*1024);                   \
    }                                                                         \
  } while (0)

  f32x16 oa0, oa1;
  #pragma unroll
  for (int r = 0; r < 16; ++r) { oa0[r] = 0.f; oa1[r] = 0.f; }
  float l_ = 0.f;

  // prologue: tile 0 -> buf0
  STAGE12(0, 0);
  asm volatile("s_waitcnt vmcnt(0)" ::: "memory");
  __syncthreads();

  int cur = 0;
  for (int t = 0; t < 16; ++t) {
    if (t < 15) STAGE12(t + 1, cur ^ 1);   // async into other buffer

    const unsigned short (*Kc)[64] =
        (const unsigned short(*)[64])(smem_dyn + cur*16384 + grp*8192);
    const unsigned short (*Vc)[64] =
        (const unsigned short(*)[64])(smem_dyn + 32768 + cur*16384 + grp*8192);

    // ---- S^T: two 32x32 tiles (k' subtiles 0-31 / 32-63), K=64 in 4 steps
    f32x16 sa0, sa1;
    #pragma unroll
    for (int r = 0; r < 16; ++r) { sa0[r] = 0.f; sa1[r] = 0.f; }
    __builtin_amdgcn_s_setprio(1);
    #pragma unroll
    for (int step = 0; step < 4; ++step) {
      bf16x8 af0 = *(const bf16x8*)&Kc[l31     ][SWZ(l31, step*16 + hi*8)];
      bf16x8 af1 = *(const bf16x8*)&Kc[32 + l31][SWZ(l31, step*16 + hi*8)];
      sa0 = __builtin_amdgcn_mfma_f32_32x32x16_bf16(af0, qf[step], sa0, 0, 0, 0);
      sa1 = __builtin_amdgcn_mfma_f32_32x32x16_bf16(af1, qf[step], sa1, 0, 0, 0);
    }
    __builtin_amdgcn_s_setprio(0);

    // ---- no-max softmax; pack bf16 pairs pk[r2] = (p[2r2], p[2r2+1])
    float ps = 0.f;
    unsigned pk0[8], pk1[8];
    #pragma unroll
    for (int r2 = 0; r2 < 8; ++r2) {
      float p0 = exp2_fast(sa0[2*r2]);
      float p1 = exp2_fast(sa0[2*r2 + 1]);
      ps += p0 + p1;
      pk0[r2] = (unsigned)pk2(p0, p1);
    }
    #pragma unroll
    for (int r2 = 0; r2 < 8; ++r2) {
      float p0 = exp2_fast(sa1[2*r2]);
      float p1 = exp2_fast(sa1[2*r2 + 1]);
      ps += p0 + p1;
      pk1[r2] = (unsigned)pk2(p0, p1);
    }
    ps += __shfl_xor(ps, 32, 64);   // lanes l, l+32 share q = lane&31
    l_ += ps;

    // ---- O^T += V^T P^T: k' chunks c = 0..3; B-frag via permlane32_swap
    __builtin_amdgcn_s_setprio(1);
    #pragma unroll
    for (int c = 0; c < 4; ++c) {
      const int c1 = c & 1;
      unsigned X, Z, Y, W;
      if (c < 2) { X = pk0[4*c1+0]; Z = pk0[4*c1+1]; Y = pk0[4*c1+2]; W = pk0[4*c1+3]; }
      else       { X = pk1[4*c1+0]; Z = pk1[4*c1+1]; Y = pk1[4*c1+2]; W = pk1[4*c1+3]; }
      asm volatile("v_permlane32_swap_b32 %0, %1" : "+v"(X), "+v"(Y));
      asm volatile("v_permlane32_swap_b32 %0, %1" : "+v"(Z), "+v"(W));
      int4 pw = { (int)X, (int)Z, (int)Y, (int)W };   // j01, j23, j45, j67
      bf16x8 pf = __builtin_bit_cast(bf16x8, pw);
      bf16x8 vf0 = *(const bf16x8*)&Vc[l31     ][SWZ(l31, c*16 + hi*8)];
      bf16x8 vf1 = *(const bf16x8*)&Vc[32 + l31][SWZ(l31, c*16 + hi*8)];
      oa0 = __builtin_amdgcn_mfma_f32_32x32x16_bf16(vf0, pf, oa0, 0, 0, 0);
      oa1 = __builtin_amdgcn_mfma_f32_32x32x16_bf16(vf1, pf, oa1, 0, 0, 0);
    }
    __builtin_amdgcn_s_setprio(0);

    // next buffer ready (loads covered by compute); reads of cur complete
    asm volatile("s_waitcnt vmcnt(0)" ::: "memory");
    __syncthreads();
    cur ^= 1;
  }
#undef STAGE12

  // ---- 2-way merge (plain sums; LDS tiles dead)
  float* cob = (float*)smem_dyn;            // [64 d][64 q] f32, 16 KB
  float* cml = (float*)(smem_dyn + 16384);  // [64] f32
  const int qloc = qw*32 + l31;
  if (grp == 1) {
    #pragma unroll
    for (int reg = 0; reg < 16; ++reg) {
      int dr = (reg & 3) + 8*(reg >> 2) + 4*hi;
      cob[(dr     )*64 + qloc] = oa0[reg];
      cob[(dr + 32)*64 + qloc] = oa1[reg];
    }
    cml[qloc] = l_;   // lanes l and l+32 write identical post-shfl value
  }
  __syncthreads();
  if (grp == 0) {
    float linv = 1.0f / (l_ + cml[qloc]);
    float* op = o + ((size_t)(b*2048 + qb*64 + qloc))*256 + h*64;
    #pragma unroll
    for (int dt = 0; dt < 2; ++dt) {
      #pragma unroll
      for (int rr = 0; rr < 4; ++rr) {
        const int dbase = dt*32 + 8*rr + 4*hi;
        float4 qv = *(const float4*)(op + dbase);
        float4 st;
        #pragma unroll
        for (int j = 0; j < 4; ++j) {
          float own = dt ? oa1[4*rr + j] : oa0[4*rr + j];
          float oth = cob[(dbase + j)*64 + qloc];
          ((float*)&st)[j] = ((const float*)&qv)[j] + (own + oth) * linv;
        }
        *(float4*)(op + dbase) = st;
      }
    }
  }
}

// ---------------------------------------------------------------------------
// fused_out (validated, byte-identical): LN0 + res+relu(GEMM Wo) + LN1.
// ---------------------------------------------------------------------------
__global__ __launch_bounds__(512) void fused_out(
    const float* __restrict__ x, const float* __restrict__ Wo,
    const float* __restrict__ bo,
    const float* __restrict__ g0v, const float* __restrict__ b0v,
    const float* __restrict__ g1v, const float* __restrict__ b1v,
    float* __restrict__ y)
{
  __shared__ __align__(16) unsigned short As[32][256];
  __shared__ __align__(16) unsigned short Ws[256][64];
  __shared__ float mu_[32], rs_[32];
  float* P = (float*)&Ws[0][0];

  const int tid = threadIdx.x;
  const int w = tid >> 6, lane = tid & 63;
  const int l15 = lane & 15, g = lane >> 4;
  const int r0 = blockIdx.x * 32;

  {
    float4 g4 = *(const float4*)(g0v + lane*4);
    float4 b4 = *(const float4*)(b0v + lane*4);
    #pragma unroll
    for (int rr = 0; rr < 4; ++rr) {
      int m = w*4 + rr;
      const float* xr = x + (size_t)(r0 + m) * 256;
      float4 v = *(const float4*)(xr + lane*4);
      float s = v.x + v.y + v.z + v.w;
      #pragma unroll
      for (int mk = 1; mk <= 32; mk <<= 1) s += __shfl_xor(s, mk, 64);
      float mu = s * (1.0f/256.0f);
      float dx = v.x-mu, dy = v.y-mu, dz = v.z-mu, dw = v.w-mu;
      float qq = dx*dx + dy*dy + dz*dz + dw*dw;
      #pragma unroll
      for (int mk = 1; mk <= 32; mk <<= 1) qq += __shfl_xor(qq, mk, 64);
      float rstd = rsqrtf(qq * (1.0f/256.0f) + 1e-5f);
      if (lane == 0) { mu_[m] = mu; rs_[m] = rstd; }
      float nx = dx*rstd*g4.x + b4.x;
      float ny = dy*rstd*g4.y + b4.y;
      float nz = dz*rstd*g4.z + b4.z;
      float nw = dw*rstd*g4.w + b4.w;
      int2 pv = { pk2(nx, ny), pk2(nz, nw) };
      *(int2*)&As[m][SWZ(m, lane*4)] = pv;
    }
  }
  __syncthreads();

  const int m0 = (w >> 2) * 16;
  const int e0 = (w & 3) * 64;
  f32x4 acc4[4];
  #pragma unroll
  for (int j = 0; j < 4; ++j)
    #pragma unroll
    for (int r = 0; r < 4; ++r) acc4[j][r] = 0.f;

  for (int k0 = 0; k0 < 256; k0 += 64) {
    if (k0) __syncthreads();
    {
      const int ch = tid & 7;
      const int er = tid >> 3;
      #pragma unroll
      for (int p = 0; p < 4; ++p) {
        int e = p*64 + er;
        const float* wp = Wo + (size_t)e*256 + k0 + ch*8;
        float4 u0 = *(const float4*)wp;
        float4 u1 = *(const float4*)(wp + 4);
        int4 pk = { pk2(u0.x,u0.y), pk2(u0.z,u0.w), pk2(u1.x,u1.y), pk2(u1.z,u1.w) };
        *(int4*)&Ws[e][SWZ(e, ch*8)] = pk;
      }
    }
    __syncthreads();
    __builtin_amdgcn_s_setprio(1);
    #pragma unroll
    for (int ds_ = 0; ds_ < 2; ++ds_) {
      int ma = m0 + l15;
      bf16x8 af = *(const bf16x8*)&As[ma][SWZ(ma, k0 + ds_*32 + g*8)];
      #pragma unroll
      for (int j = 0; j < 4; ++j) {
        int er = e0 + j*16 + l15;
        bf16x8 bfv = *(const bf16x8*)&Ws[er][SWZ(er, ds_*32 + g*8)];
        acc4[j] = __builtin_amdgcn_mfma_f32_16x16x32_bf16(af, bfv, acc4[j], 0, 0, 0);
      }
    }
    __builtin_amdgcn_s_setprio(0);
  }
  __syncthreads();

  #pragma unroll
  for (int j = 0; j < 4; ++j) {
    int e = e0 + j*16 + l15;
    float bov = bo[e], g0e = g0v[e], b0e = b0v[e];
    #pragma unroll
    for (int r = 0; r < 4; ++r) {
      int m = m0 + g*4 + r;
      float xv = x[(size_t)(r0 + m)*256 + e];
      float resv = (xv - mu_[m]) * rs_[m] * g0e + b0e;
      float val = acc4[j][r] + bov;
      P[m*256 + e] = resv + fmaxf(val, 0.f);
    }
  }
  __syncthreads();

  {
    float4 g4 = *(const float4*)(g1v + lane*4);
    float4 b4 = *(const float4*)(b1v + lane*4);
    #pragma unroll
    for (int rr = 0; rr < 4; ++rr) {
      int m = w*4 + rr;
      float4 v = *(const float4*)&P[m*256 + lane*4];
      float s = v.x + v.y + v.z + v.w;
      #pragma unroll
      for (int mk = 1; mk <= 32; mk <<= 1) s += __shfl_xor(s, mk, 64);
      float mu = s * (1.0f/256.0f);
      float dx = v.x-mu, dy = v.y-mu, dz = v.z-mu, dw = v.w-mu;
      float qq = dx*dx + dy*dy + dz*dz + dw*dw;
      #pragma unroll
      for (int mk = 1; mk <= 32; mk <<= 1) qq += __shfl_xor(qq, mk, 64);
      float rstd = rsqrtf(qq * (1.0f/256.0f) + 1e-5f);
      float4 o;
      o.x = dx*rstd*g4.x + b4.x; o.y = dy*rstd*g4.y + b4.y;
      o.z = dz*rstd*g4.z + b4.z; o.w = dw*rstd*g4.w + b4.w;
      *(float4*)(y + (size_t)(r0 + m)*256 + lane*4) = o;
    }
  }
}

// ---------------------------------------------------------------------------
extern "C" void kernel_launch(void* const* d_in, const int* in_sizes, int n_in,
                              void* d_out, int out_size, void* d_ws, size_t ws_size,
                              hipStream_t stream) {
  const float* Q  = (const float*)d_in[0];
  const float* K  = (const float*)d_in[1];
  const float* Wq = (const float*)d_in[2];
  const float* bq = (const float*)d_in[3];
  const float* Wk = (const float*)d_in[4];
  const float* bk = (const float*)d_in[5];
  const float* Wv = (const float*)d_in[6];
  const float* bv = (const float*)d_in[7];
  const float* Wo = (const float*)d_in[8];
  const float* bo = (const float*)d_in[9];
  const float* g0 = (const float*)d_in[10];
  const float* b0 = (const float*)d_in[11];
  const float* g1 = (const float*)d_in[12];
  const float* b1 = (const float*)d_in[13];
  float* out = (float*)d_out;

  const size_t SZ = (size_t)4 * 2048 * 256;
  if (ws_size < 2 * SZ * sizeof(unsigned short)) return;  // need 8 MB

  unsigned short* kbf = (unsigned short*)d_ws;
  unsigned short* vtb = kbf + SZ;

  const int ATTN_LDS = 65536;
  hipFuncSetAttribute((const void*)attn_mfma12,
                      hipFuncAttributeMaxDynamicSharedMemorySize, ATTN_LDS);

  proj2_kernel<<<dim3(2, 128, 3), dim3(256), 0, stream>>>(
      Q, K, Wq, bq, Wk, bk, Wv, bv, out, kbf, vtb);
  attn_mfma12<<<dim3(512), dim3(256), ATTN_LDS, stream>>>(out, kbf, vtb, out);
  fused_out<<<dim3(256), dim3(512), 0, stream>>>(out, Wo, bo, g0, b0, g1, b1, out);
}